// Round 8
// baseline (343.964 us; speedup 1.0000x reference)
//
#include <hip/hip_runtime.h>

typedef unsigned short u16;
typedef unsigned int u32;
typedef unsigned long long u64;
typedef __attribute__((ext_vector_type(8))) short short8;
typedef __attribute__((ext_vector_type(4))) float f32x4;

#define ICAPS 512
#define IDIM 128
#define NFLAT 512  // NCAPS(16) * ODIM(32)

__device__ __forceinline__ float b2f(u16 h) {
    union { u32 u; float f; } x; x.u = ((u32)h) << 16; return x.f;
}
__device__ __forceinline__ u16 f2b(float f) {
    union { float f; u32 u; } x; x.f = f;
    return (u16)((x.u + 0x7FFFu + ((x.u >> 16) & 1u)) >> 16);
}

// ---------------------------------------------------------------------------
// GEMM: u_hat[b,i,n] = sum_k x[b,i,k]*W[i,j(n),k,d(n)], n=j*32+d. fp32 inputs.
// R6-proven interior + LDS-repack epilogue. Also zeroes cnt[64] for the
// route-phase-1 last-block fold (runs 2 dispatches before it; stream order
// + kernel-boundary flush guarantee visibility).
// ---------------------------------------------------------------------------
__global__ __launch_bounds__(256, 4) void gemm_kernel(const float* __restrict__ x,
                                                      const float* __restrict__ W,
                                                      u16* __restrict__ uhat,
                                                      u32* __restrict__ cnt) {
    __shared__ __align__(16) u16 As[64 * 136];   // x[b][k] bf16, pitch 136
    const int orig = blockIdx.x;
    const int chunk = (orig >> 3) & 3;
    const int i = ((orig >> 5) << 3) | (orig & 7);
    const int t = threadIdx.x;

    if (orig == 0 && t < 64) cnt[t] = 0;   // init last-block counters

    // Stage A: 64 rows x 128 k of x for this i; 2048 float4, 8/thread
    {
        const float4* xa = (const float4*)x;
        float4 av[8];
        #pragma unroll
        for (int l = 0; l < 8; ++l) {
            int id = l * 256 + t;
            av[l] = xa[(size_t)((id >> 5) * ICAPS + i) * 32 + (id & 31)];
        }
        #pragma unroll
        for (int l = 0; l < 8; ++l) {
            int id = l * 256 + t;
            int row = id >> 5, kq = id & 31;
            union { u16 h[4]; u64 q; } pk;
            pk.h[0] = f2b(av[l].x); pk.h[1] = f2b(av[l].y);
            pk.h[2] = f2b(av[l].z); pk.h[3] = f2b(av[l].w);
            *(u64*)&As[row * 136 + kq * 4] = pk.q;
        }
    }
    __syncthreads();

    const int lane = t & 63;
    const int w = t >> 6;
    const int ln = lane & 15;
    const int q = lane >> 4;

    const float* colbase[2];
    #pragma unroll
    for (int nt = 0; nt < 2; ++nt) {
        int c = (2 * w + nt) * 16 + ln;
        int jj = c >> 5, d = c & 31;
        colbase[nt] = W + (size_t)(i * 16 + chunk * 4 + jj) * 128 * 32 + d;
    }

    f32x4 acc[4][2] = {};
    #pragma unroll
    for (int ks = 0; ks < 4; ++ks) {
        const int ko = ks * 32 + q * 8;
        short8 a[4], bb[2];
        #pragma unroll
        for (int mt = 0; mt < 4; ++mt)
            a[mt] = *(const short8*)&As[(mt * 16 + ln) * 136 + ko];
        #pragma unroll
        for (int nt = 0; nt < 2; ++nt) {
            const float* p = colbase[nt] + (size_t)ko * 32;
            float wv[8];
            #pragma unroll
            for (int e = 0; e < 8; ++e) wv[e] = p[e * 32];   // offset e*128B imm
            #pragma unroll
            for (int e = 0; e < 8; ++e) bb[nt][e] = (short)f2b(wv[e]);
        }
        #pragma unroll
        for (int mt = 0; mt < 4; ++mt)
            #pragma unroll
            for (int nt = 0; nt < 2; ++nt)
                acc[mt][nt] = __builtin_amdgcn_mfma_f32_16x16x32_bf16(a[mt], bb[nt], acc[mt][nt], 0, 0, 0);
    }

    // Epilogue: repack C via LDS (As dead; 64x136 u16 fits).
    // C/D: col = lane&15, row = q*4 + reg (m89/m91-verified)
    __syncthreads();   // all waves done reading As
    #pragma unroll
    for (int mt = 0; mt < 4; ++mt)
        #pragma unroll
        for (int nt = 0; nt < 2; ++nt) {
            int nl = (2 * w + nt) * 16 + ln;
            #pragma unroll
            for (int r = 0; r < 4; ++r) {
                int brow = mt * 16 + q * 4 + r;
                As[brow * 136 + nl] = f2b(acc[mt][nt][r]);
            }
        }
    __syncthreads();
    // 4 passes: 16 rows/pass, 16 lanes/row x 8 u16 (16B) -> 256B/row coalesced
    #pragma unroll
    for (int p = 0; p < 4; ++p) {
        int brow = p * 16 + (t >> 4);
        int col8 = (t & 15) * 8;
        uint4 v = *(const uint4*)&As[brow * 136 + col8];
        *(uint4*)&uhat[((size_t)brow * ICAPS + i) * NFLAT + chunk * 128 + col8] = v;
    }
}

// ---------------------------------------------------------------------------
// p0: q0[bx][n] = sum_{i in slice} uhat[b,i,n]; bx = b*16+ch. No atomics.
// ---------------------------------------------------------------------------
__global__ __launch_bounds__(256) void p0_kernel(const u16* __restrict__ uhat,
                                                 float* __restrict__ q0) {
    __shared__ __align__(16) float red[4][NFLAT];
    const int b = blockIdx.x >> 4;
    const int ch = blockIdx.x & 15;
    const int t = threadIdx.x;
    const int wv = t >> 6, l = t & 63;
    float acc[8] = {0.f, 0.f, 0.f, 0.f, 0.f, 0.f, 0.f, 0.f};
    for (int ii = 0; ii < 8; ++ii) {
        int i = ch * 32 + wv * 8 + ii;
        union { uint4 v; u16 h[8]; } tmp;
        tmp.v = *(const uint4*)&uhat[((size_t)b * ICAPS + i) * NFLAT + l * 8];
        #pragma unroll
        for (int e = 0; e < 8; ++e) acc[e] += b2f(tmp.h[e]);
    }
    #pragma unroll
    for (int e = 0; e < 8; ++e) red[wv][l * 8 + e] = acc[e];
    __syncthreads();
    q0[(size_t)blockIdx.x * NFLAT + t] =
        red[0][t] + red[1][t] + red[2][t] + red[3][t];
    q0[(size_t)blockIdx.x * NFLAT + 256 + t] =
        red[0][t + 256] + red[1][t + 256] + red[2][t + 256] + red[3][t + 256];
}

// ---------------------------------------------------------------------------
// route: combine folded in (R4). phase 0: s = sum(q0)/16; osum = squash(s);
// ch==0 persists osum -> osum0. phase 1: s = sum(q1); osum = osum0+squash(s).
// Softmax without max-sub (R3); __fdividef.
// R7: phase 1 folds fin via per-b last-block: after qout partials are
// stored, threadfence + atomicAdd(cnt[b]); the 16th block for b reads the 16
// q2 partials (L2-hot) and does fin's squash+store. No spin, no deadlock
// possible: every block does bounded work regardless of arrival order.
// ---------------------------------------------------------------------------
__global__ __launch_bounds__(256) void route_kernel(const u16* __restrict__ uhat,
                                                    const float* __restrict__ qin,
                                                    float* __restrict__ osum0,
                                                    float* __restrict__ qout,
                                                    u32* __restrict__ cnt,
                                                    float* __restrict__ out,
                                                    int phase) {
    __shared__ float osum[NFLAT];
    __shared__ __align__(16) float red[4][NFLAT];
    const int b = blockIdx.x >> 4;
    const int ch = blockIdx.x & 15;
    const int t = threadIdx.x;
    // ---- in-block combine + squash (t covers all 512 n as 256x2) ----
    {
        const int j = t >> 4, g = t & 15;   // 16 threads per j, 2 d's each
        const int n0 = j * 32 + 2 * g;
        const float* qb = qin + (size_t)(b * 16) * NFLAT;
        float v0 = 0.f, v1 = 0.f;
        #pragma unroll
        for (int c2 = 0; c2 < 16; ++c2) {
            v0 += qb[c2 * NFLAT + n0];
            v1 += qb[c2 * NFLAT + n0 + 1];
        }
        if (phase == 0) { v0 *= 0.0625f; v1 *= 0.0625f; }
        float p = v0 * v0 + v1 * v1;
        p += __shfl_xor(p, 1); p += __shfl_xor(p, 2);
        p += __shfl_xor(p, 4); p += __shfl_xor(p, 8);
        float sc = (p / (1.f + p)) / sqrtf(p + 1e-7f);
        float o0 = sc * v0, o1 = sc * v1;
        if (phase == 0) {
            osum[n0] = o0; osum[n0 + 1] = o1;
            if (ch == 0) {
                osum0[b * NFLAT + n0]     = o0;
                osum0[b * NFLAT + n0 + 1] = o1;
            }
        } else {
            osum[n0]     = o0 + osum0[b * NFLAT + n0];
            osum[n0 + 1] = o1 + osum0[b * NFLAT + n0 + 1];
        }
    }
    __syncthreads();
    const int wv = t >> 6, l = t & 63;
    float os[8], acc[8];
    #pragma unroll
    for (int e = 0; e < 8; ++e) { os[e] = osum[l * 8 + e]; acc[e] = 0.f; }
    for (int ii = 0; ii < 8; ++ii) {
        int i = ch * 32 + wv * 8 + ii;
        union { uint4 v; u16 h[8]; } tmp;
        tmp.v = *(const uint4*)&uhat[((size_t)b * ICAPS + i) * NFLAT + l * 8];
        float u[8];
        #pragma unroll
        for (int e = 0; e < 8; ++e) u[e] = b2f(tmp.h[e]);
        float d = 0.f;
        #pragma unroll
        for (int e = 0; e < 8; ++e) d += u[e] * os[e];
        d += __shfl_xor(d, 1); d += __shfl_xor(d, 2);   // quad = one j
        float ex = __expf(d);                            // no max-sub: |d|<~20
        float ss = ex;
        ss += __shfl_xor(ss, 4);  ss += __shfl_xor(ss, 8);
        ss += __shfl_xor(ss, 16); ss += __shfl_xor(ss, 32);
        float c = __fdividef(ex, ss);
        #pragma unroll
        for (int e = 0; e < 8; ++e) acc[e] += c * u[e];
    }
    #pragma unroll
    for (int e = 0; e < 8; ++e) red[wv][l * 8 + e] = acc[e];
    __syncthreads();
    qout[(size_t)blockIdx.x * NFLAT + t] =
        red[0][t] + red[1][t] + red[2][t] + red[3][t];
    qout[(size_t)blockIdx.x * NFLAT + 256 + t] =
        red[0][t + 256] + red[1][t + 256] + red[2][t + 256] + red[3][t + 256];

    // ---- phase-1 only: per-b last block does fin for this b ----
    if (phase == 1) {
        __shared__ u32 done;
        __threadfence();                         // release q2 partial (device scope)
        if (t == 0) done = atomicAdd(&cnt[b], 1);
        __syncthreads();
        if (done == 15) {                        // uniform branch: last of 16
            __threadfence();                     // acquire: other blocks' partials
            const int j = t >> 4, g = t & 15;
            const int n0 = j * 32 + 2 * g;
            const float* qb = qout + (size_t)(b * 16) * NFLAT;
            float v0 = 0.f, v1 = 0.f;
            #pragma unroll
            for (int c2 = 0; c2 < 16; ++c2) {
                v0 += qb[c2 * NFLAT + n0];
                v1 += qb[c2 * NFLAT + n0 + 1];
            }
            float p = v0 * v0 + v1 * v1;
            p += __shfl_xor(p, 1); p += __shfl_xor(p, 2);
            p += __shfl_xor(p, 4); p += __shfl_xor(p, 8);
            float sc = (p / (1.f + p)) / sqrtf(p + 1e-7f);
            out[b * NFLAT + n0]     = sc * v0;
            out[b * NFLAT + n0 + 1] = sc * v1;
        }
    }
}

extern "C" void kernel_launch(void* const* d_in, const int* in_sizes, int n_in,
                              void* d_out, int out_size, void* d_ws, size_t ws_size,
                              hipStream_t stream) {
    // fp32 inputs. Resolve by element count.
    const float* x = nullptr;
    const float* W = nullptr;
    for (int a = 0; a < n_in; ++a) {
        if (in_sizes[a] == 64 * 512 * 128) x = (const float*)d_in[a];
        else if (in_sizes[a] == 512 * 16 * 128 * 32) W = (const float*)d_in[a];
    }
    if (!x) x = (const float*)d_in[0];
    if (!W) W = (const float*)d_in[1];

    char* ws = (char*)d_ws;
    const size_t U = 2ull * 64 * 512 * 512;          // uhat bytes = 33.5 MB
    u16*   uhat = (u16*)ws;
    float* q0 = (float*)(ws + U);                    // 1024*512 f32 = 2 MB
    float* q1 = (float*)(ws + U + (2ull << 20));
    float* q2 = (float*)(ws + U + (4ull << 20));
    float* osum0 = (float*)(ws + U + (6ull << 20));  // 64*512 f32 = 128 KB
    u32*   cnt = (u32*)(ws + U + (6ull << 20) + (256ull << 10));  // 64 u32
    float* out = (float*)d_out;

    hipLaunchKernelGGL(gemm_kernel, dim3(2048), dim3(256), 0, stream, x, W, uhat, cnt);
    hipLaunchKernelGGL(p0_kernel, dim3(1024), dim3(256), 0, stream, uhat, q0);
    hipLaunchKernelGGL(route_kernel, dim3(1024), dim3(256), 0, stream, uhat, q0, osum0, q1, cnt, out, 0);
    hipLaunchKernelGGL(route_kernel, dim3(1024), dim3(256), 0, stream, uhat, q1, osum0, q2, cnt, out, 1);
}

// Round 9
// 240.368 us; speedup vs baseline: 1.4310x; 1.4310x over previous
//
#include <hip/hip_runtime.h>

typedef unsigned short u16;
typedef unsigned int u32;
typedef unsigned long long u64;
typedef __attribute__((ext_vector_type(8))) short short8;
typedef __attribute__((ext_vector_type(4))) float f32x4;

#define ICAPS 512
#define IDIM 128
#define NFLAT 512  // NCAPS(16) * ODIM(32)

__device__ __forceinline__ float b2f(u16 h) {
    union { u32 u; float f; } x; x.u = ((u32)h) << 16; return x.f;
}
__device__ __forceinline__ u16 f2b(float f) {
    union { float f; u32 u; } x; x.f = f;
    return (u16)((x.u + 0x7FFFu + ((x.u >> 16) & 1u)) >> 16);
}

// ---------------------------------------------------------------------------
// GEMM: u_hat[b,i,n] = sum_k x[b,i,k]*W[i,j(n),k,d(n)], n=j*32+d. fp32 inputs.
// Terminal config (R6-proven, 240.6 µs): W direct-to-register (read once
// grid-wide), XCD-sibling blockIdx decode, LDS-repack coalesced epilogue.
// R8 lesson baked in: NO device-scope fences/atomics anywhere — kernel
// boundaries are the cheap sync on MI355X (per-block __threadfence costs
// ~0.1 µs/block in L2 writeback storms; R8 counters: 2.4% VALU, 2.7% HBM).
// ---------------------------------------------------------------------------
__global__ __launch_bounds__(256, 4) void gemm_kernel(const float* __restrict__ x,
                                                      const float* __restrict__ W,
                                                      u16* __restrict__ uhat) {
    __shared__ __align__(16) u16 As[64 * 136];   // x[b][k] bf16, pitch 136
    const int orig = blockIdx.x;
    const int chunk = (orig >> 3) & 3;
    const int i = ((orig >> 5) << 3) | (orig & 7);
    const int t = threadIdx.x;

    // Stage A: 64 rows x 128 k of x for this i; 2048 float4, 8/thread
    {
        const float4* xa = (const float4*)x;
        float4 av[8];
        #pragma unroll
        for (int l = 0; l < 8; ++l) {
            int id = l * 256 + t;
            av[l] = xa[(size_t)((id >> 5) * ICAPS + i) * 32 + (id & 31)];
        }
        #pragma unroll
        for (int l = 0; l < 8; ++l) {
            int id = l * 256 + t;
            int row = id >> 5, kq = id & 31;
            union { u16 h[4]; u64 q; } pk;
            pk.h[0] = f2b(av[l].x); pk.h[1] = f2b(av[l].y);
            pk.h[2] = f2b(av[l].z); pk.h[3] = f2b(av[l].w);
            *(u64*)&As[row * 136 + kq * 4] = pk.q;
        }
    }
    __syncthreads();

    const int lane = t & 63;
    const int w = t >> 6;
    const int ln = lane & 15;
    const int q = lane >> 4;

    const float* colbase[2];
    #pragma unroll
    for (int nt = 0; nt < 2; ++nt) {
        int c = (2 * w + nt) * 16 + ln;
        int jj = c >> 5, d = c & 31;
        colbase[nt] = W + (size_t)(i * 16 + chunk * 4 + jj) * 128 * 32 + d;
    }

    f32x4 acc[4][2] = {};
    #pragma unroll
    for (int ks = 0; ks < 4; ++ks) {
        const int ko = ks * 32 + q * 8;
        short8 a[4], bb[2];
        #pragma unroll
        for (int mt = 0; mt < 4; ++mt)
            a[mt] = *(const short8*)&As[(mt * 16 + ln) * 136 + ko];
        #pragma unroll
        for (int nt = 0; nt < 2; ++nt) {
            const float* p = colbase[nt] + (size_t)ko * 32;
            float wv[8];
            #pragma unroll
            for (int e = 0; e < 8; ++e) wv[e] = p[e * 32];   // offset e*128B imm
            #pragma unroll
            for (int e = 0; e < 8; ++e) bb[nt][e] = (short)f2b(wv[e]);
        }
        #pragma unroll
        for (int mt = 0; mt < 4; ++mt)
            #pragma unroll
            for (int nt = 0; nt < 2; ++nt)
                acc[mt][nt] = __builtin_amdgcn_mfma_f32_16x16x32_bf16(a[mt], bb[nt], acc[mt][nt], 0, 0, 0);
    }

    // Epilogue: repack C via LDS (As dead; 64x136 u16 fits).
    // C/D: col = lane&15, row = q*4 + reg (m89/m91-verified)
    __syncthreads();   // all waves done reading As
    #pragma unroll
    for (int mt = 0; mt < 4; ++mt)
        #pragma unroll
        for (int nt = 0; nt < 2; ++nt) {
            int nl = (2 * w + nt) * 16 + ln;
            #pragma unroll
            for (int r = 0; r < 4; ++r) {
                int brow = mt * 16 + q * 4 + r;
                As[brow * 136 + nl] = f2b(acc[mt][nt][r]);
            }
        }
    __syncthreads();
    // 4 passes: 16 rows/pass, 16 lanes/row x 8 u16 (16B) -> 256B/row coalesced
    #pragma unroll
    for (int p = 0; p < 4; ++p) {
        int brow = p * 16 + (t >> 4);
        int col8 = (t & 15) * 8;
        uint4 v = *(const uint4*)&As[brow * 136 + col8];
        *(uint4*)&uhat[((size_t)brow * ICAPS + i) * NFLAT + chunk * 128 + col8] = v;
    }
}

// ---------------------------------------------------------------------------
// p0: q0[bx][n] = sum_{i in slice} uhat[b,i,n]; bx = b*16+ch. No atomics.
// ---------------------------------------------------------------------------
__global__ __launch_bounds__(256) void p0_kernel(const u16* __restrict__ uhat,
                                                 float* __restrict__ q0) {
    __shared__ __align__(16) float red[4][NFLAT];
    const int b = blockIdx.x >> 4;
    const int ch = blockIdx.x & 15;
    const int t = threadIdx.x;
    const int wv = t >> 6, l = t & 63;
    float acc[8] = {0.f, 0.f, 0.f, 0.f, 0.f, 0.f, 0.f, 0.f};
    for (int ii = 0; ii < 8; ++ii) {
        int i = ch * 32 + wv * 8 + ii;
        union { uint4 v; u16 h[8]; } tmp;
        tmp.v = *(const uint4*)&uhat[((size_t)b * ICAPS + i) * NFLAT + l * 8];
        #pragma unroll
        for (int e = 0; e < 8; ++e) acc[e] += b2f(tmp.h[e]);
    }
    #pragma unroll
    for (int e = 0; e < 8; ++e) red[wv][l * 8 + e] = acc[e];
    __syncthreads();
    q0[(size_t)blockIdx.x * NFLAT + t] =
        red[0][t] + red[1][t] + red[2][t] + red[3][t];
    q0[(size_t)blockIdx.x * NFLAT + 256 + t] =
        red[0][t + 256] + red[1][t + 256] + red[2][t + 256] + red[3][t + 256];
}

// ---------------------------------------------------------------------------
// route: combine folded in (R4). phase 0: s = sum(q0)/16; osum = squash(s);
// ch==0 persists osum -> osum0. phase 1: s = sum(q1); osum = osum0+squash(s).
// Softmax without max-sub (R3); __fdividef.
// ---------------------------------------------------------------------------
__global__ __launch_bounds__(256) void route_kernel(const u16* __restrict__ uhat,
                                                    const float* __restrict__ qin,
                                                    float* __restrict__ osum0,
                                                    float* __restrict__ qout,
                                                    int phase) {
    __shared__ float osum[NFLAT];
    __shared__ __align__(16) float red[4][NFLAT];
    const int b = blockIdx.x >> 4;
    const int ch = blockIdx.x & 15;
    const int t = threadIdx.x;
    // ---- in-block combine + squash (t covers all 512 n as 256x2) ----
    {
        const int j = t >> 4, g = t & 15;   // 16 threads per j, 2 d's each
        const int n0 = j * 32 + 2 * g;
        const float* qb = qin + (size_t)(b * 16) * NFLAT;
        float v0 = 0.f, v1 = 0.f;
        #pragma unroll
        for (int c2 = 0; c2 < 16; ++c2) {
            v0 += qb[c2 * NFLAT + n0];
            v1 += qb[c2 * NFLAT + n0 + 1];
        }
        if (phase == 0) { v0 *= 0.0625f; v1 *= 0.0625f; }
        float p = v0 * v0 + v1 * v1;
        p += __shfl_xor(p, 1); p += __shfl_xor(p, 2);
        p += __shfl_xor(p, 4); p += __shfl_xor(p, 8);
        float sc = (p / (1.f + p)) / sqrtf(p + 1e-7f);
        float o0 = sc * v0, o1 = sc * v1;
        if (phase == 0) {
            osum[n0] = o0; osum[n0 + 1] = o1;
            if (ch == 0) {
                osum0[b * NFLAT + n0]     = o0;
                osum0[b * NFLAT + n0 + 1] = o1;
            }
        } else {
            osum[n0]     = o0 + osum0[b * NFLAT + n0];
            osum[n0 + 1] = o1 + osum0[b * NFLAT + n0 + 1];
        }
    }
    __syncthreads();
    const int wv = t >> 6, l = t & 63;
    float os[8], acc[8];
    #pragma unroll
    for (int e = 0; e < 8; ++e) { os[e] = osum[l * 8 + e]; acc[e] = 0.f; }
    for (int ii = 0; ii < 8; ++ii) {
        int i = ch * 32 + wv * 8 + ii;
        union { uint4 v; u16 h[8]; } tmp;
        tmp.v = *(const uint4*)&uhat[((size_t)b * ICAPS + i) * NFLAT + l * 8];
        float u[8];
        #pragma unroll
        for (int e = 0; e < 8; ++e) u[e] = b2f(tmp.h[e]);
        float d = 0.f;
        #pragma unroll
        for (int e = 0; e < 8; ++e) d += u[e] * os[e];
        d += __shfl_xor(d, 1); d += __shfl_xor(d, 2);   // quad = one j
        float ex = __expf(d);                            // no max-sub: |d|<~20
        float ss = ex;
        ss += __shfl_xor(ss, 4);  ss += __shfl_xor(ss, 8);
        ss += __shfl_xor(ss, 16); ss += __shfl_xor(ss, 32);
        float c = __fdividef(ex, ss);
        #pragma unroll
        for (int e = 0; e < 8; ++e) acc[e] += c * u[e];
    }
    #pragma unroll
    for (int e = 0; e < 8; ++e) red[wv][l * 8 + e] = acc[e];
    __syncthreads();
    qout[(size_t)blockIdx.x * NFLAT + t] =
        red[0][t] + red[1][t] + red[2][t] + red[3][t];
    qout[(size_t)blockIdx.x * NFLAT + 256 + t] =
        red[0][t + 256] + red[1][t + 256] + red[2][t + 256] + red[3][t + 256];
}

// fin: s2[b][n] = sum_ch q2; out = squash(s2), fp32
__global__ __launch_bounds__(256) void fin_kernel(const float* __restrict__ q2,
                                                  float* __restrict__ out) {
    const int b = blockIdx.x, t = threadIdx.x;
    const int j = t >> 4, g = t & 15;
    const int n0 = j * 32 + 2 * g;
    float v0 = 0.f, v1 = 0.f;
    #pragma unroll
    for (int ch = 0; ch < 16; ++ch) {
        v0 += q2[(size_t)(b * 16 + ch) * NFLAT + n0];
        v1 += q2[(size_t)(b * 16 + ch) * NFLAT + n0 + 1];
    }
    float p = v0 * v0 + v1 * v1;
    p += __shfl_xor(p, 1); p += __shfl_xor(p, 2);
    p += __shfl_xor(p, 4); p += __shfl_xor(p, 8);
    float sc = (p / (1.f + p)) / sqrtf(p + 1e-7f);
    out[b * NFLAT + n0]     = sc * v0;
    out[b * NFLAT + n0 + 1] = sc * v1;
}

extern "C" void kernel_launch(void* const* d_in, const int* in_sizes, int n_in,
                              void* d_out, int out_size, void* d_ws, size_t ws_size,
                              hipStream_t stream) {
    // fp32 inputs. Resolve by element count.
    const float* x = nullptr;
    const float* W = nullptr;
    for (int a = 0; a < n_in; ++a) {
        if (in_sizes[a] == 64 * 512 * 128) x = (const float*)d_in[a];
        else if (in_sizes[a] == 512 * 16 * 128 * 32) W = (const float*)d_in[a];
    }
    if (!x) x = (const float*)d_in[0];
    if (!W) W = (const float*)d_in[1];

    char* ws = (char*)d_ws;
    const size_t U = 2ull * 64 * 512 * 512;          // uhat bytes = 33.5 MB
    u16*   uhat = (u16*)ws;
    float* q0 = (float*)(ws + U);                    // 1024*512 f32 = 2 MB
    float* q1 = (float*)(ws + U + (2ull << 20));
    float* q2 = (float*)(ws + U + (4ull << 20));
    float* osum0 = (float*)(ws + U + (6ull << 20));  // 64*512 f32 = 128 KB
    float* out = (float*)d_out;

    hipLaunchKernelGGL(gemm_kernel, dim3(2048), dim3(256), 0, stream, x, W, uhat);
    hipLaunchKernelGGL(p0_kernel, dim3(1024), dim3(256), 0, stream, uhat, q0);
    hipLaunchKernelGGL(route_kernel, dim3(1024), dim3(256), 0, stream, uhat, q0, osum0, q1, 0);
    hipLaunchKernelGGL(route_kernel, dim3(1024), dim3(256), 0, stream, uhat, q1, osum0, q2, 1);
    hipLaunchKernelGGL(fin_kernel, dim3(64), dim3(256), 0, stream, q2, out);
}